// Round 6
// baseline (687.261 us; speedup 1.0000x reference)
//
#include <hip/hip_runtime.h>
#include <math.h>

#define EPSF 1e-8f

constexpr int B = 262144;
constexpr int T = 128;
constexpr int E = 5;
constexpr int K = 20;
constexpr int SGRID = 2048;              // state blocks (2048*256*16 float4 = B*T/4 exact)
constexpr int VGRID = 1024;              // survival blocks (1024*256 = B exact)
constexpr int TOTAL = SGRID + VGRID;     // 3072

// ws layout (floats): [0,SGRID) s-partials | [SGRID,2*SGRID) mask-partials
//                     | [2*SGRID, 2*SGRID+VGRID) ll-partials | [2*SGRID+VGRID] arrival counter (uint)
// Partials are unconditionally overwritten each call; counter is memset to 0 per call.

__device__ __forceinline__ float agent_load(const float* p) {
    return __hip_atomic_load(p, __ATOMIC_RELAXED, __HIP_MEMORY_SCOPE_AGENT);
}

__global__ __launch_bounds__(256) void k_main(const float4* __restrict__ pred,
                                              const float4* __restrict__ targ,
                                              const float4* __restrict__ mask,
                                              const float* __restrict__ hz,
                                              const float* __restrict__ et,
                                              const float* __restrict__ ei,
                                              float* __restrict__ ws,
                                              unsigned* __restrict__ cnt,
                                              float* __restrict__ out) {
    const int tid = threadIdx.x;
    const int bid = blockIdx.x;
    const bool surv_role = (bid % 3 == 2);   // 1024 of 3072, interleaved across dispatch

    if (surv_role) {
        // ---------------- survival role ----------------
        const int vblk = bid / 3;
        int b = vblk * 256 + tid;
        float ll = 0.f;
        #pragma unroll
        for (int e = 0; e < E; ++e) {
            float t = et[b * E + e];
            float ind = ei[b * E + e];
            // searchsorted(bounds={0.5,...,10.0}, t, 'left') == #bounds < t.
            // bounds are exact multiples of 0.5: j*0.5 < t  <=>  j < 2t (exact).
            float u = 2.0f * t;
            int idx = (int)floorf(u);
            if ((float)idx == u) idx -= 1;
            idx = min(max(idx, 0), K - 1);
            const float4* row = (const float4*)(hz + ((size_t)e * B + b) * K);
            float cum = 0.f, ls = 0.f, lp = 0.f;
            #pragma unroll
            for (int q = 0; q < K / 4; ++q) {
                float4 v = row[q];
                float xs[4] = {v.x, v.y, v.z, v.w};
                #pragma unroll
                for (int j = 0; j < 4; ++j) {
                    int k = q * 4 + j;
                    float p = 1.0f / (1.0f + __expf(-xs[j]));
                    if (k == idx) { ls = cum; lp = __logf(p + EPSF); }
                    cum += __logf(1.0f - p + EPSF);   // after the check: exclusive prefix
                }
            }
            ll += ls + (ind > 0.5f ? lp : 0.0f);
        }
        #pragma unroll
        for (int off = 32; off > 0; off >>= 1) ll += __shfl_down(ll, off);
        __shared__ float sl[4];
        int wid = tid >> 6;
        if ((tid & 63) == 0) sl[wid] = ll;
        __syncthreads();
        if (tid == 0)
            ws[2 * SGRID + vblk] = sl[0] + sl[1] + sl[2] + sl[3];
    } else {
        // ---------------- state role: 16 float4 positions/thread, A/B ping-pong --------
        const int sblk = bid - (bid + 1) / 3;   // 0..SGRID-1 over non-survival blocks
        const int tb4 = sblk * 4096 + tid;
        float s = 0.f, m = 0.f;

        float4 pa0, pa1, ta0, ta1, wa0, wa1;
        float4 pb0, pb1, tb0, tb1, wb0, wb1;

#define LOADA(c) \
    pa0 = pred[tb4 + (c + 0) * 256]; pa1 = pred[tb4 + (c + 1) * 256]; \
    ta0 = targ[tb4 + (c + 0) * 256]; ta1 = targ[tb4 + (c + 1) * 256]; \
    wa0 = mask[tb4 + (c + 0) * 256]; wa1 = mask[tb4 + (c + 1) * 256];

#define LOADB(c) \
    pb0 = pred[tb4 + (c + 0) * 256]; pb1 = pred[tb4 + (c + 1) * 256]; \
    tb0 = targ[tb4 + (c + 0) * 256]; tb1 = targ[tb4 + (c + 1) * 256]; \
    wb0 = mask[tb4 + (c + 0) * 256]; wb1 = mask[tb4 + (c + 1) * 256];

// NOTE: macro params must not be named x/y/z/w (member-access tokens get substituted)
#define C1(P_, T_, W_) { float d_; \
    d_ = P_.x - T_.x; s += d_ * d_ * W_.x; m += W_.x; \
    d_ = P_.y - T_.y; s += d_ * d_ * W_.y; m += W_.y; \
    d_ = P_.z - T_.z; s += d_ * d_ * W_.z; m += W_.z; \
    d_ = P_.w - T_.w; s += d_ * d_ * W_.w; m += W_.w; }

#define CONSA C1(pa0, ta0, wa0) C1(pa1, ta1, wa1)
#define CONSB C1(pb0, tb0, wb0) C1(pb1, tb1, wb1)

        LOADA(0)
        LOADB(2)
        CONSA
        LOADA(4)
        CONSB
        LOADB(6)
        CONSA
        LOADA(8)
        CONSB
        LOADB(10)
        CONSA
        LOADA(12)
        CONSB
        LOADB(14)
        CONSA
        CONSB

#undef LOADA
#undef LOADB
#undef C1
#undef CONSA
#undef CONSB

        #pragma unroll
        for (int off = 32; off > 0; off >>= 1) {
            s += __shfl_down(s, off);
            m += __shfl_down(m, off);
        }
        __shared__ float ss[4], sm[4];
        int wid = tid >> 6;
        if ((tid & 63) == 0) { ss[wid] = s; sm[wid] = m; }
        __syncthreads();
        if (tid == 0) {
            ws[sblk]         = ss[0] + ss[1] + ss[2] + ss[3];
            ws[SGRID + sblk] = sm[0] + sm[1] + sm[2] + sm[3];
        }
    }

    // ---------------- arrival + last-block final reduction ----------------
    __shared__ unsigned arrival;
    __threadfence();                       // publish this block's partials (agent scope)
    if (tid == 0) arrival = atomicAdd(cnt, 1u);
    __syncthreads();
    if (arrival != TOTAL - 1) return;

    __threadfence();                       // acquire: others' partials now visible
    float s = 0.f, m = 0.f, l = 0.f;
    #pragma unroll
    for (int i = 0; i < SGRID / 256; ++i) {
        s += agent_load(&ws[tid + i * 256]);
        m += agent_load(&ws[SGRID + tid + i * 256]);
    }
    #pragma unroll
    for (int i = 0; i < VGRID / 256; ++i)
        l += agent_load(&ws[2 * SGRID + tid + i * 256]);
    #pragma unroll
    for (int off = 32; off > 0; off >>= 1) {
        s += __shfl_down(s, off);
        m += __shfl_down(m, off);
        l += __shfl_down(l, off);
    }
    __shared__ float as[4], am[4], al[4];
    int wid = tid >> 6;
    if ((tid & 63) == 0) { as[wid] = s; am[wid] = m; al[wid] = l; }
    __syncthreads();
    if (tid == 0) {
        float S = as[0] + as[1] + as[2] + as[3];
        float M = am[0] + am[1] + am[2] + am[3];
        float L = al[0] + al[1] + al[2] + al[3];
        out[0] = S / (M + EPSF) - L / (float)(E * B);
    }
}

extern "C" void kernel_launch(void* const* d_in, const int* in_sizes, int n_in,
                              void* d_out, int out_size, void* d_ws, size_t ws_size,
                              hipStream_t stream) {
    const float* pred = (const float*)d_in[0];
    const float* hz   = (const float*)d_in[1];
    const float* targ = (const float*)d_in[2];
    const float* mask = (const float*)d_in[3];
    const float* et   = (const float*)d_in[4];
    const float* ei   = (const float*)d_in[5];
    float* out = (float*)d_out;
    float* ws  = (float*)d_ws;
    unsigned* cnt = (unsigned*)(ws + 2 * SGRID + VGRID);

    // zero the arrival counter (ws is NOT re-poisoned between replays; poison is 0xAA)
    hipMemsetAsync(cnt, 0, sizeof(unsigned), stream);

    hipLaunchKernelGGL(k_main, dim3(TOTAL), dim3(256), 0, stream,
                       (const float4*)pred, (const float4*)targ,
                       (const float4*)mask, hz, et, ei, ws, cnt, out);
}

// Round 7
// 103.144 us; speedup vs baseline: 6.6631x; 6.6631x over previous
//
#include <hip/hip_runtime.h>
#include <math.h>

#define EPSF 1e-8f

constexpr int B = 262144;
constexpr int T = 128;
constexpr int E = 5;
constexpr int K = 20;
constexpr int SGRID = 2048;              // state blocks (2048*256*16 float4 = B*T/4 exact)
constexpr int VGRID = 1024;              // survival blocks (1024*256 = B exact)
constexpr int TOTAL = SGRID + VGRID;     // 3072

// ws layout (floats): [0,SGRID) s-partials | [SGRID,2*SGRID) mask-partials
//                     | [2*SGRID, 2*SGRID+VGRID) ll-partials
// Every slot is unconditionally overwritten each call -> no init needed.
// NOTE (round 6 lesson): no device/agent fences, no single-kernel arrival counter —
// agent-scope fences on gfx950 flush per-XCD L2 and cost far more than a 2nd dispatch.

__global__ __launch_bounds__(256) void k_main(const float4* __restrict__ pred,
                                              const float4* __restrict__ targ,
                                              const float4* __restrict__ mask,
                                              const float* __restrict__ hz,
                                              const float* __restrict__ et,
                                              const float* __restrict__ ei,
                                              float* __restrict__ ws) {
    const int tid = threadIdx.x;
    const int bid = blockIdx.x;

    if (bid % 3 == 2) {
        // ---------------- survival role (1/3 of blocks, interleaved) ----------------
        const int vblk = bid / 3;
        int b = vblk * 256 + tid;
        float ll = 0.f;
        #pragma unroll
        for (int e = 0; e < E; ++e) {
            float t = et[b * E + e];
            float ind = ei[b * E + e];
            // searchsorted(bounds={0.5,...,10.0}, t, 'left') == #bounds < t.
            // bounds are exact multiples of 0.5: j*0.5 < t  <=>  j < 2t (exact).
            float u = 2.0f * t;
            int idx = (int)floorf(u);
            if ((float)idx == u) idx -= 1;
            idx = min(max(idx, 0), K - 1);
            const float4* row = (const float4*)(hz + ((size_t)e * B + b) * K);
            float cum = 0.f, ls = 0.f, lp = 0.f;
            #pragma unroll
            for (int q = 0; q < K / 4; ++q) {
                float4 v = row[q];
                float xs[4] = {v.x, v.y, v.z, v.w};
                #pragma unroll
                for (int j = 0; j < 4; ++j) {
                    int k = q * 4 + j;
                    float p = 1.0f / (1.0f + __expf(-xs[j]));
                    if (k == idx) { ls = cum; lp = __logf(p + EPSF); }
                    cum += __logf(1.0f - p + EPSF);   // after the check: exclusive prefix
                }
            }
            ll += ls + (ind > 0.5f ? lp : 0.0f);
        }
        #pragma unroll
        for (int off = 32; off > 0; off >>= 1) ll += __shfl_down(ll, off);
        __shared__ float sl[4];
        int wid = tid >> 6;
        if ((tid & 63) == 0) sl[wid] = ll;
        __syncthreads();
        if (tid == 0)
            ws[2 * SGRID + vblk] = sl[0] + sl[1] + sl[2] + sl[3];
        return;
    }

    // ---------------- state role: 16 float4 positions/thread, A/B ping-pong -------------
    const int sblk = bid - (bid + 1) / 3;   // 0..SGRID-1 over non-survival blocks
    const int tb4 = sblk * 4096 + tid;
    float s = 0.f, m = 0.f;

    float4 pa0, pa1, ta0, ta1, wa0, wa1;
    float4 pb0, pb1, tb0, tb1, wb0, wb1;

#define LOADA(c) \
    pa0 = pred[tb4 + (c + 0) * 256]; pa1 = pred[tb4 + (c + 1) * 256]; \
    ta0 = targ[tb4 + (c + 0) * 256]; ta1 = targ[tb4 + (c + 1) * 256]; \
    wa0 = mask[tb4 + (c + 0) * 256]; wa1 = mask[tb4 + (c + 1) * 256];

#define LOADB(c) \
    pb0 = pred[tb4 + (c + 0) * 256]; pb1 = pred[tb4 + (c + 1) * 256]; \
    tb0 = targ[tb4 + (c + 0) * 256]; tb1 = targ[tb4 + (c + 1) * 256]; \
    wb0 = mask[tb4 + (c + 0) * 256]; wb1 = mask[tb4 + (c + 1) * 256];

// NOTE: macro params must not be named x/y/z/w (member-access tokens get substituted)
#define C1(P_, T_, W_) { float d_; \
    d_ = P_.x - T_.x; s += d_ * d_ * W_.x; m += W_.x; \
    d_ = P_.y - T_.y; s += d_ * d_ * W_.y; m += W_.y; \
    d_ = P_.z - T_.z; s += d_ * d_ * W_.z; m += W_.z; \
    d_ = P_.w - T_.w; s += d_ * d_ * W_.w; m += W_.w; }

#define CONSA C1(pa0, ta0, wa0) C1(pa1, ta1, wa1)
#define CONSB C1(pb0, tb0, wb0) C1(pb1, tb1, wb1)

    LOADA(0)
    LOADB(2)
    CONSA
    LOADA(4)
    CONSB
    LOADB(6)
    CONSA
    LOADA(8)
    CONSB
    LOADB(10)
    CONSA
    LOADA(12)
    CONSB
    LOADB(14)
    CONSA
    CONSB

#undef LOADA
#undef LOADB
#undef C1
#undef CONSA
#undef CONSB

    #pragma unroll
    for (int off = 32; off > 0; off >>= 1) {
        s += __shfl_down(s, off);
        m += __shfl_down(m, off);
    }
    __shared__ float ss[4], sm[4];
    int wid = tid >> 6;
    if ((tid & 63) == 0) { ss[wid] = s; sm[wid] = m; }
    __syncthreads();
    if (tid == 0) {
        ws[sblk]         = ss[0] + ss[1] + ss[2] + ss[3];
        ws[SGRID + sblk] = sm[0] + sm[1] + sm[2] + sm[3];
    }
}

__global__ __launch_bounds__(256) void k_fin(const float* __restrict__ ws,
                                             float* __restrict__ out) {
    int tid = threadIdx.x;
    float s = 0.f, m = 0.f, l = 0.f;
    #pragma unroll
    for (int i = 0; i < SGRID / 256; ++i) {
        s += ws[tid + i * 256];
        m += ws[SGRID + tid + i * 256];
    }
    #pragma unroll
    for (int i = 0; i < VGRID / 256; ++i)
        l += ws[2 * SGRID + tid + i * 256];
    #pragma unroll
    for (int off = 32; off > 0; off >>= 1) {
        s += __shfl_down(s, off);
        m += __shfl_down(m, off);
        l += __shfl_down(l, off);
    }
    __shared__ float as[4], am[4], al[4];
    int wid = tid >> 6;
    if ((tid & 63) == 0) { as[wid] = s; am[wid] = m; al[wid] = l; }
    __syncthreads();
    if (tid == 0) {
        float S = as[0] + as[1] + as[2] + as[3];
        float M = am[0] + am[1] + am[2] + am[3];
        float L = al[0] + al[1] + al[2] + al[3];
        out[0] = S / (M + EPSF) - L / (float)(E * B);
    }
}

extern "C" void kernel_launch(void* const* d_in, const int* in_sizes, int n_in,
                              void* d_out, int out_size, void* d_ws, size_t ws_size,
                              hipStream_t stream) {
    const float* pred = (const float*)d_in[0];
    const float* hz   = (const float*)d_in[1];
    const float* targ = (const float*)d_in[2];
    const float* mask = (const float*)d_in[3];
    const float* et   = (const float*)d_in[4];
    const float* ei   = (const float*)d_in[5];
    float* out = (float*)d_out;
    float* ws  = (float*)d_ws;

    hipLaunchKernelGGL(k_main, dim3(TOTAL), dim3(256), 0, stream,
                       (const float4*)pred, (const float4*)targ,
                       (const float4*)mask, hz, et, ei, ws);

    hipLaunchKernelGGL(k_fin, dim3(1), dim3(256), 0, stream, ws, out);
}

// Round 8
// 96.550 us; speedup vs baseline: 7.1182x; 1.0683x over previous
//
#include <hip/hip_runtime.h>
#include <math.h>

#define EPSF 1e-8f

constexpr int B = 262144;
constexpr int T = 128;
constexpr int E = 5;
constexpr int K = 20;
constexpr int SGRID = 2048;              // state blocks (2048*256*16 float4 = B*T/4 exact)
constexpr int VGRID = 1024;              // survival blocks (1024*256 = B exact)
constexpr int TOTAL = SGRID + VGRID;     // 3072

// ws layout (floats): [0,SGRID) s-partials | [SGRID,2*SGRID) mask-partials
//                     | [2*SGRID, 2*SGRID+VGRID) ll-partials
// Every slot is unconditionally overwritten each call -> no init needed.
// Lessons kept: (r6) no agent fences / single-kernel finalize — L2 flush costs 5x;
// (r7) survival-first beats interleave — keep VALU-heavy blocks at dispatch front.

__global__ __launch_bounds__(256) void k_main(const float4* __restrict__ pred,
                                              const float4* __restrict__ targ,
                                              const float4* __restrict__ mask,
                                              const float* __restrict__ hz,
                                              const float* __restrict__ et,
                                              const float* __restrict__ ei,
                                              float* __restrict__ ws) {
    const int tid = threadIdx.x;

    if (blockIdx.x < VGRID) {
        // ---------------- survival role (dispatches first, overlaps state stream) -------
        int b = blockIdx.x * 256 + tid;
        float ll = 0.f;
        #pragma unroll
        for (int e = 0; e < E; ++e) {
            float t = et[b * E + e];
            float ind = ei[b * E + e];
            // searchsorted(bounds={0.5,...,10.0}, t, 'left') == #bounds < t.
            // bounds are exact multiples of 0.5: j*0.5 < t  <=>  j < 2t (exact).
            float u = 2.0f * t;
            int idx = (int)floorf(u);
            if ((float)idx == u) idx -= 1;
            idx = min(max(idx, 0), K - 1);
            const float4* row = (const float4*)(hz + ((size_t)e * B + b) * K);
            float cum = 0.f, ls = 0.f, xsel = 0.f;
            #pragma unroll
            for (int q = 0; q < K / 4; ++q) {
                float4 v = row[q];
                float xs[4] = {v.x, v.y, v.z, v.w};
                #pragma unroll
                for (int j = 0; j < 4; ++j) {
                    int k = q * 4 + j;
                    float p = 1.0f / (1.0f + __expf(-xs[j]));
                    bool hit = (k == idx);
                    ls = hit ? cum : ls;          // exclusive prefix at idx
                    xsel = hit ? xs[j] : xsel;    // defer the log to after the loop
                    cum += __logf(1.0f - p + EPSF);
                }
            }
            float psel = 1.0f / (1.0f + __expf(-xsel));
            float lp = __logf(psel + EPSF);       // single TRANS op instead of 20 masked
            ll += ls + (ind > 0.5f ? lp : 0.0f);
        }
        #pragma unroll
        for (int off = 32; off > 0; off >>= 1) ll += __shfl_down(ll, off);
        __shared__ float sl[4];
        int wid = tid >> 6;
        if ((tid & 63) == 0) sl[wid] = ll;
        __syncthreads();
        if (tid == 0)
            ws[2 * SGRID + blockIdx.x] = sl[0] + sl[1] + sl[2] + sl[3];
        return;
    }

    // ---------------- state role: 16 float4 positions/thread, A/B ping-pong -------------
    const int sblk = blockIdx.x - VGRID;
    const int tb4 = sblk * 4096 + tid;
    float s = 0.f, m = 0.f;

    float4 pa0, pa1, ta0, ta1, wa0, wa1;
    float4 pb0, pb1, tb0, tb1, wb0, wb1;

#define LOADA(c) \
    pa0 = pred[tb4 + (c + 0) * 256]; pa1 = pred[tb4 + (c + 1) * 256]; \
    ta0 = targ[tb4 + (c + 0) * 256]; ta1 = targ[tb4 + (c + 1) * 256]; \
    wa0 = mask[tb4 + (c + 0) * 256]; wa1 = mask[tb4 + (c + 1) * 256];

#define LOADB(c) \
    pb0 = pred[tb4 + (c + 0) * 256]; pb1 = pred[tb4 + (c + 1) * 256]; \
    tb0 = targ[tb4 + (c + 0) * 256]; tb1 = targ[tb4 + (c + 1) * 256]; \
    wb0 = mask[tb4 + (c + 0) * 256]; wb1 = mask[tb4 + (c + 1) * 256];

// NOTE: macro params must not be named x/y/z/w (member-access tokens get substituted)
#define C1(P_, T_, W_) { float d_; \
    d_ = P_.x - T_.x; s += d_ * d_ * W_.x; m += W_.x; \
    d_ = P_.y - T_.y; s += d_ * d_ * W_.y; m += W_.y; \
    d_ = P_.z - T_.z; s += d_ * d_ * W_.z; m += W_.z; \
    d_ = P_.w - T_.w; s += d_ * d_ * W_.w; m += W_.w; }

#define CONSA C1(pa0, ta0, wa0) C1(pa1, ta1, wa1)
#define CONSB C1(pb0, tb0, wb0) C1(pb1, tb1, wb1)

    LOADA(0)
    LOADB(2)
    CONSA
    LOADA(4)
    CONSB
    LOADB(6)
    CONSA
    LOADA(8)
    CONSB
    LOADB(10)
    CONSA
    LOADA(12)
    CONSB
    LOADB(14)
    CONSA
    CONSB

#undef LOADA
#undef LOADB
#undef C1
#undef CONSA
#undef CONSB

    #pragma unroll
    for (int off = 32; off > 0; off >>= 1) {
        s += __shfl_down(s, off);
        m += __shfl_down(m, off);
    }
    __shared__ float ss[4], sm[4];
    int wid = tid >> 6;
    if ((tid & 63) == 0) { ss[wid] = s; sm[wid] = m; }
    __syncthreads();
    if (tid == 0) {
        ws[sblk]         = ss[0] + ss[1] + ss[2] + ss[3];
        ws[SGRID + sblk] = sm[0] + sm[1] + sm[2] + sm[3];
    }
}

__global__ __launch_bounds__(256) void k_fin(const float* __restrict__ ws,
                                             float* __restrict__ out) {
    int tid = threadIdx.x;
    float s = 0.f, m = 0.f, l = 0.f;
    #pragma unroll
    for (int i = 0; i < SGRID / 256; ++i) {
        s += ws[tid + i * 256];
        m += ws[SGRID + tid + i * 256];
    }
    #pragma unroll
    for (int i = 0; i < VGRID / 256; ++i)
        l += ws[2 * SGRID + tid + i * 256];
    #pragma unroll
    for (int off = 32; off > 0; off >>= 1) {
        s += __shfl_down(s, off);
        m += __shfl_down(m, off);
        l += __shfl_down(l, off);
    }
    __shared__ float as[4], am[4], al[4];
    int wid = tid >> 6;
    if ((tid & 63) == 0) { as[wid] = s; am[wid] = m; al[wid] = l; }
    __syncthreads();
    if (tid == 0) {
        float S = as[0] + as[1] + as[2] + as[3];
        float M = am[0] + am[1] + am[2] + am[3];
        float L = al[0] + al[1] + al[2] + al[3];
        out[0] = S / (M + EPSF) - L / (float)(E * B);
    }
}

extern "C" void kernel_launch(void* const* d_in, const int* in_sizes, int n_in,
                              void* d_out, int out_size, void* d_ws, size_t ws_size,
                              hipStream_t stream) {
    const float* pred = (const float*)d_in[0];
    const float* hz   = (const float*)d_in[1];
    const float* targ = (const float*)d_in[2];
    const float* mask = (const float*)d_in[3];
    const float* et   = (const float*)d_in[4];
    const float* ei   = (const float*)d_in[5];
    float* out = (float*)d_out;
    float* ws  = (float*)d_ws;

    hipLaunchKernelGGL(k_main, dim3(TOTAL), dim3(256), 0, stream,
                       (const float4*)pred, (const float4*)targ,
                       (const float4*)mask, hz, et, ei, ws);

    hipLaunchKernelGGL(k_fin, dim3(1), dim3(256), 0, stream, ws, out);
}

// Round 9
// 85.757 us; speedup vs baseline: 8.0141x; 1.1259x over previous
//
#include <hip/hip_runtime.h>
#include <math.h>

#define EPSF 1e-8f

constexpr int B = 262144;
constexpr int T = 128;
constexpr int E = 5;
constexpr int K = 20;
constexpr int SGRID = 2048;              // state blocks (2048*256*16 float4 = B*T/4 exact)
constexpr int VGRID = 1024;              // survival blocks (1024*256 = B exact)
constexpr int TOTAL = SGRID + VGRID;     // 3072

// ws layout (floats): [0,SGRID) s-partials | [SGRID,2*SGRID) mask-partials
//                     | [2*SGRID, 2*SGRID+VGRID) ll-partials
// Lessons kept: (r6) no agent fences / single-kernel finalize — L2 flush costs 5x;
// (r7) survival-first beats interleave. (r9 test): NT loads on read-once state streams.

typedef float v4f __attribute__((ext_vector_type(4)));

__device__ __forceinline__ v4f ntload(const v4f* p) {
    return __builtin_nontemporal_load(p);
}

__global__ __launch_bounds__(256) void k_main(const v4f* __restrict__ pred,
                                              const v4f* __restrict__ targ,
                                              const v4f* __restrict__ mask,
                                              const float* __restrict__ hz,
                                              const float* __restrict__ et,
                                              const float* __restrict__ ei,
                                              float* __restrict__ ws) {
    const int tid = threadIdx.x;

    if (blockIdx.x < VGRID) {
        // ---------------- survival role (dispatches first, overlaps state stream) -------
        int b = blockIdx.x * 256 + tid;
        float ll = 0.f;
        #pragma unroll
        for (int e = 0; e < E; ++e) {
            float t = et[b * E + e];
            float ind = ei[b * E + e];
            // searchsorted(bounds={0.5,...,10.0}, t, 'left') == #bounds < t.
            // bounds are exact multiples of 0.5: j*0.5 < t  <=>  j < 2t (exact).
            float u = 2.0f * t;
            int idx = (int)floorf(u);
            if ((float)idx == u) idx -= 1;
            idx = min(max(idx, 0), K - 1);
            const v4f* row = (const v4f*)(hz + ((size_t)e * B + b) * K);
            float cum = 0.f, ls = 0.f, xsel = 0.f;
            #pragma unroll
            for (int q = 0; q < K / 4; ++q) {
                v4f v = row[q];   // cached: hazard array is L3-resident across replays
                float xs[4] = {v.x, v.y, v.z, v.w};
                #pragma unroll
                for (int j = 0; j < 4; ++j) {
                    int k = q * 4 + j;
                    float p = 1.0f / (1.0f + __expf(-xs[j]));
                    bool hit = (k == idx);
                    ls = hit ? cum : ls;          // exclusive prefix at idx
                    xsel = hit ? xs[j] : xsel;    // defer the hit-log to after the loop
                    cum += __logf(1.0f - p + EPSF);
                }
            }
            float psel = 1.0f / (1.0f + __expf(-xsel));
            float lp = __logf(psel + EPSF);
            ll += ls + (ind > 0.5f ? lp : 0.0f);
        }
        #pragma unroll
        for (int off = 32; off > 0; off >>= 1) ll += __shfl_down(ll, off);
        __shared__ float sl[4];
        int wid = tid >> 6;
        if ((tid & 63) == 0) sl[wid] = ll;
        __syncthreads();
        if (tid == 0)
            ws[2 * SGRID + blockIdx.x] = sl[0] + sl[1] + sl[2] + sl[3];
        return;
    }

    // ------- state role: 16 float4/thread, A/B ping-pong, NON-TEMPORAL loads -----------
    const int sblk = blockIdx.x - VGRID;
    const int tb4 = sblk * 4096 + tid;
    float s = 0.f, m = 0.f;

    v4f pa0, pa1, ta0, ta1, wa0, wa1;
    v4f pb0, pb1, tb0, tb1, wb0, wb1;

#define LOADA(c) \
    pa0 = ntload(pred + tb4 + (c + 0) * 256); pa1 = ntload(pred + tb4 + (c + 1) * 256); \
    ta0 = ntload(targ + tb4 + (c + 0) * 256); ta1 = ntload(targ + tb4 + (c + 1) * 256); \
    wa0 = ntload(mask + tb4 + (c + 0) * 256); wa1 = ntload(mask + tb4 + (c + 1) * 256);

#define LOADB(c) \
    pb0 = ntload(pred + tb4 + (c + 0) * 256); pb1 = ntload(pred + tb4 + (c + 1) * 256); \
    tb0 = ntload(targ + tb4 + (c + 0) * 256); tb1 = ntload(targ + tb4 + (c + 1) * 256); \
    wb0 = ntload(mask + tb4 + (c + 0) * 256); wb1 = ntload(mask + tb4 + (c + 1) * 256);

// NOTE: macro params must not be named x/y/z/w (member-access tokens get substituted)
#define C1(P_, T_, W_) { float d_; \
    d_ = P_.x - T_.x; s += d_ * d_ * W_.x; m += W_.x; \
    d_ = P_.y - T_.y; s += d_ * d_ * W_.y; m += W_.y; \
    d_ = P_.z - T_.z; s += d_ * d_ * W_.z; m += W_.z; \
    d_ = P_.w - T_.w; s += d_ * d_ * W_.w; m += W_.w; }

#define CONSA C1(pa0, ta0, wa0) C1(pa1, ta1, wa1)
#define CONSB C1(pb0, tb0, wb0) C1(pb1, tb1, wb1)

    LOADA(0)
    LOADB(2)
    CONSA
    LOADA(4)
    CONSB
    LOADB(6)
    CONSA
    LOADA(8)
    CONSB
    LOADB(10)
    CONSA
    LOADA(12)
    CONSB
    LOADB(14)
    CONSA
    CONSB

#undef LOADA
#undef LOADB
#undef C1
#undef CONSA
#undef CONSB

    #pragma unroll
    for (int off = 32; off > 0; off >>= 1) {
        s += __shfl_down(s, off);
        m += __shfl_down(m, off);
    }
    __shared__ float ss[4], sm[4];
    int wid = tid >> 6;
    if ((tid & 63) == 0) { ss[wid] = s; sm[wid] = m; }
    __syncthreads();
    if (tid == 0) {
        ws[sblk]         = ss[0] + ss[1] + ss[2] + ss[3];
        ws[SGRID + sblk] = sm[0] + sm[1] + sm[2] + sm[3];
    }
}

__global__ __launch_bounds__(256) void k_fin(const float* __restrict__ ws,
                                             float* __restrict__ out) {
    int tid = threadIdx.x;
    float s = 0.f, m = 0.f, l = 0.f;
    #pragma unroll
    for (int i = 0; i < SGRID / 256; ++i) {
        s += ws[tid + i * 256];
        m += ws[SGRID + tid + i * 256];
    }
    #pragma unroll
    for (int i = 0; i < VGRID / 256; ++i)
        l += ws[2 * SGRID + tid + i * 256];
    #pragma unroll
    for (int off = 32; off > 0; off >>= 1) {
        s += __shfl_down(s, off);
        m += __shfl_down(m, off);
        l += __shfl_down(l, off);
    }
    __shared__ float as[4], am[4], al[4];
    int wid = tid >> 6;
    if ((tid & 63) == 0) { as[wid] = s; am[wid] = m; al[wid] = l; }
    __syncthreads();
    if (tid == 0) {
        float S = as[0] + as[1] + as[2] + as[3];
        float M = am[0] + am[1] + am[2] + am[3];
        float L = al[0] + al[1] + al[2] + al[3];
        out[0] = S / (M + EPSF) - L / (float)(E * B);
    }
}

extern "C" void kernel_launch(void* const* d_in, const int* in_sizes, int n_in,
                              void* d_out, int out_size, void* d_ws, size_t ws_size,
                              hipStream_t stream) {
    const float* pred = (const float*)d_in[0];
    const float* hz   = (const float*)d_in[1];
    const float* targ = (const float*)d_in[2];
    const float* mask = (const float*)d_in[3];
    const float* et   = (const float*)d_in[4];
    const float* ei   = (const float*)d_in[5];
    float* out = (float*)d_out;
    float* ws  = (float*)d_ws;

    hipLaunchKernelGGL(k_main, dim3(TOTAL), dim3(256), 0, stream,
                       (const v4f*)pred, (const v4f*)targ,
                       (const v4f*)mask, hz, et, ei, ws);

    hipLaunchKernelGGL(k_fin, dim3(1), dim3(256), 0, stream, ws, out);
}